// Round 5
// baseline (7302.155 us; speedup 1.0000x reference)
//
#include <hip/hip_runtime.h>
#include <cstdint>
#include <cstddef>

// ---------------------------------------------------------------------------
// Persistent pipelined 3-layer LSTM on MI355X — v5.
//  = R4 (verified) compute/reduce/epilogue; NEW: single poll site per tick,
//  register-staged ring reads (h_prev[t-1] + prefetch h_in[t+1] issued
//  together after B1; h_in LDS-write deferred past compute so its MALL
//  latency hides under MFMA), 5 barriers instead of 7. h_prev unified into
//  LDS region1 for all layers; partials in a dedicated 32KB area (96KB LDS
//  total -> guaranteed 1 block/CU).
// ---------------------------------------------------------------------------

typedef __attribute__((ext_vector_type(8))) short bf16x8;
typedef __attribute__((ext_vector_type(4))) float f32x4;
typedef __attribute__((ext_vector_type(2))) unsigned long long u64x2;

#define TT    1024
#define RINGD 8
#define NBL   64
#define NGRID (3*NBL + 1)

#define OFF_W1   0ULL
#define OFF_W2   (OFF_W1 + 2048ULL*512*2)
#define OFF_W3   (OFF_W2 + 2048ULL*1024*2)
#define OFF_BIAS (OFF_W3 + 2048ULL*1024*2)
#define OFF_FLAG (OFF_BIAS + 3ULL*2048*4)
#define OFF_RING (OFF_FLAG + 4096ULL)
#define NEED_BIG (OFF_RING + 3ULL*TT*64*512*2)

__device__ __forceinline__ unsigned short f2bf(float f) {
  unsigned int u = __float_as_uint(f);
  unsigned int r = (u + 0x7fffu + ((u >> 16) & 1u)) >> 16;   // RNE
  return (unsigned short)r;
}
__device__ __forceinline__ float bf2f(unsigned short h) {
  return __uint_as_float(((unsigned int)h) << 16);
}
__device__ __forceinline__ float sigmf_(float z) {
  return 1.f / (1.f + __expf(-z));
}
__device__ __forceinline__ float tanhf_(float z) {
  float t = __expf(-2.f * fabsf(z));
  float r = (1.f - t) / (1.f + t);
  return (z < 0.f) ? -r : r;
}

// ---------------------------------------------------------------------------
__global__ void prep_kernel(const float* __restrict__ wih1, const float* __restrict__ whh1,
                            const float* __restrict__ bih1, const float* __restrict__ bhh1,
                            const float* __restrict__ wih2, const float* __restrict__ whh2,
                            const float* __restrict__ bih2, const float* __restrict__ bhh2,
                            const float* __restrict__ wih3, const float* __restrict__ whh3,
                            const float* __restrict__ bih3, const float* __restrict__ bhh3,
                            unsigned char* ws)
{
  unsigned short* w1 = (unsigned short*)(ws + OFF_W1);
  unsigned short* w2 = (unsigned short*)(ws + OFF_W2);
  unsigned short* w3 = (unsigned short*)(ws + OFF_W3);
  float* bias = (float*)(ws + OFF_BIAS);
  int*   flags = (int*)(ws + OFF_FLAG);
  int idx = blockIdx.x * 256 + threadIdx.x;   // grid covers 2048*1024
  int j = idx >> 10, k = idx & 1023;
  if (j < 2048) {
    float v2 = (k < 512) ? wih2[j*512 + k] : whh2[j*512 + (k - 512)];
    float v3 = (k < 512) ? wih3[j*512 + k] : whh3[j*512 + (k - 512)];
    w2[j*1024 + k] = f2bf(v2);
    w3[j*1024 + k] = f2bf(v3);
    if (k < 512) w1[j*512 + k] = f2bf(whh1[j*512 + k]);
  }
  if (idx < 2048) {
    bias[idx]        = bih1[idx] + bhh1[idx];
    bias[2048 + idx] = bih2[idx] + bhh2[idx];
    bias[4096 + idx] = bih3[idx] + bhh3[idx];
  }
  if (idx < 256) flags[idx] = 0;
}

// ---------------------------------------------------------------------------
// MFMA over resident weight fragments; A from swizzled LDS.
// smemc: base such that koff>>9 selects the right region (g=0 -> pass
// region1 base so its K=512 [h_prev] reads land in region1).
template<int KSTEPS>
__device__ __forceinline__ void compute_tiles(const bf16x8 (&warr)[32], const char* smemc,
                                              int wv, int ln15, int kgrp,
                                              f32x4 (&acc)[2][4])
{
  const int k0w = wv * (KSTEPS * 32);
  const int sw  = (ln15 & 7) << 4;
  #pragma unroll
  for (int s = 0; s < KSTEPS; ++s) {
    const int koff = k0w + s*32 + kgrp*8;
    const int r    = koff >> 9;          // 0 = h_in region, 1 = h_prev region
    const int kin  = koff & 511;
    const char* ab = smemc + r*32768;
    bf16x8 a0 = *(const bf16x8*)(ab + ((ln15*1024        + kin*2) ^ sw));
    bf16x8 a1 = *(const bf16x8*)(ab + (((ln15 + 16)*1024 + kin*2) ^ sw));
    #pragma unroll
    for (int gt = 0; gt < 4; ++gt) {
      acc[0][gt] = __builtin_amdgcn_mfma_f32_16x16x32_bf16(a0, warr[gt*KSTEPS + s], acc[0][gt], 0, 0, 0);
      acc[1][gt] = __builtin_amdgcn_mfma_f32_16x16x32_bf16(a1, warr[gt*KSTEPS + s], acc[1][gt], 0, 0, 0);
    }
  }
}

// ---------------------------------------------------------------------------
__global__ __launch_bounds__(256, 1) void rnn_kernel(
    unsigned char* ws, const float* __restrict__ x,
    const float* __restrict__ wih1, const float* __restrict__ wlin,
    const float* __restrict__ blin, float* __restrict__ out, int big)
{
  // region0 (h_in) @0, region1 (h_prev) @32768, partials @65536. 96KB.
  __shared__ __align__(128) char smem[98304];
  const int tid  = threadIdx.x;
  const int lane = tid & 63;
  const int wv   = tid >> 6;
  const int SLOTS = big ? TT : RINGD;
  int* flags = (int*)(ws + OFF_FLAG);
  unsigned int* ringw = (unsigned int*)(ws + OFF_RING);
  const unsigned long long* ringq = (const unsigned long long*)(ws + OFF_RING);

  // ------------------------- output-projection block -----------------------
  if (blockIdx.x == NGRID - 1) {
    float* wl = (float*)smem;            // 512 floats
    float* op = (float*)(smem + 4096);   // 64 x 4 partials
    if (tid < 128) ((f32x4*)wl)[tid] = ((const f32x4*)wlin)[tid];
    float blv = blin[0];
    __syncthreads();
    const int ob = tid >> 2, okq = tid & 3;
    const int* fup = flags + 2*64 + lane;
    for (int t = 0; t < TT; ++t) {
      if (wv == 0) {
        for (;;) {
          int v = __hip_atomic_load(fup, __ATOMIC_RELAXED, __HIP_MEMORY_SCOPE_AGENT);
          if (__all(v >= t + 1)) break;
          __builtin_amdgcn_s_sleep(2);
        }
      }
      asm volatile("" ::: "memory");
      __syncthreads();
      const int slot = big ? t : (t & 7);
      size_t ebase = ((size_t)(2*SLOTS + slot) * 64 + ob) * 512 + (size_t)okq * 128;
      const unsigned long long* hp = ringq + (ebase >> 2);
      const float* wlp = wl + okq * 128;
      float acc = 0.f;
      if (big) {
        #pragma unroll
        for (int i = 0; i < 32; ++i) {
          unsigned long long qv = hp[i];
          acc += bf2f((unsigned short)(qv      )) * wlp[i*4 + 0];
          acc += bf2f((unsigned short)(qv >> 16)) * wlp[i*4 + 1];
          acc += bf2f((unsigned short)(qv >> 32)) * wlp[i*4 + 2];
          acc += bf2f((unsigned short)(qv >> 48)) * wlp[i*4 + 3];
        }
      } else {
        #pragma unroll
        for (int i = 0; i < 32; ++i) {
          unsigned long long qv = __hip_atomic_load(hp + i, __ATOMIC_RELAXED, __HIP_MEMORY_SCOPE_AGENT);
          acc += bf2f((unsigned short)(qv      )) * wlp[i*4 + 0];
          acc += bf2f((unsigned short)(qv >> 16)) * wlp[i*4 + 1];
          acc += bf2f((unsigned short)(qv >> 32)) * wlp[i*4 + 2];
          acc += bf2f((unsigned short)(qv >> 48)) * wlp[i*4 + 3];
        }
      }
      op[ob*4 + okq] = acc;
      __syncthreads();
      if (tid < 64)
        out[(size_t)tid * TT + t] = op[tid*4] + op[tid*4+1] + op[tid*4+2] + op[tid*4+3] + blv;
      if (tid == 0)
        __hip_atomic_store(flags + 3*64, t + 1, __ATOMIC_RELEASE, __HIP_MEMORY_SCOPE_AGENT);
      __syncthreads();
    }
    return;
  }

  // ------------------------------ layer blocks -----------------------------
  const int g  = blockIdx.x >> 6;          // 0..2
  const int q  = blockIdx.x & 63;
  const int bh = q & 1;                    // batch half
  const int nbase = (q >> 1) << 4;         // n-chunk * 16
  const unsigned short* Wg =
      (const unsigned short*)(ws + (g == 0 ? OFF_W1 : (g == 1 ? OFF_W2 : OFF_W3)));
  const float* biasg = (const float*)(ws + OFF_BIAS) + g * 2048;

  const int ln15 = lane & 15;
  const int kgrp = lane >> 4;

  // ---- resident weight fragments: 32 x bf16x8 = 128 VGPR/thread ----
  bf16x8 warr[32];
  if (g == 0) {
    #pragma unroll
    for (int gt = 0; gt < 4; ++gt)
      #pragma unroll
      for (int s = 0; s < 4; ++s)
        warr[gt*4 + s] = *(const bf16x8*)(Wg + (size_t)(gt*512 + nbase + ln15)*512
                                             + wv*128 + s*32 + kgrp*8);
  } else {
    #pragma unroll
    for (int gt = 0; gt < 4; ++gt)
      #pragma unroll
      for (int s = 0; s < 8; ++s)
        warr[gt*8 + s] = *(const bf16x8*)(Wg + (size_t)(gt*512 + nbase + ln15)*1024
                                             + wv*256 + s*32 + kgrp*8);
  }

  // epilogue cell ownership: thread -> (batch eb, n-pair n0,n0+1)
  const int eb  = tid >> 3;                // 0..31
  const int n0  = (tid & 7) << 1;          // 0,2,...,14
  const int bge = bh * 32 + eb;            // global batch
  float bsv[4][2], wxv[4][2];
  #pragma unroll
  for (int gt = 0; gt < 4; ++gt) {
    #pragma unroll
    for (int cc = 0; cc < 2; ++cc) {
      int jj = gt*512 + nbase + n0 + cc;
      bsv[gt][cc] = biasg[jj];
      wxv[gt][cc] = (g == 0) ? wih1[jj] : 0.f;
    }
  }
  float cst0 = 0.f, cst1 = 0.f;            // persistent c state

  // flags: waits narrowed to same batch-half producers (32 flags, lane&31)
  const int l31 = lane & 31;
  int* myflag = flags + g*64 + q;
  const int* fup  = flags + (g > 0 ? (g - 1)*64 : 0) + 2*l31 + bh;
  const int* fsib = flags + g*64 + 2*l31 + bh;
  const int* fdn  = (g < 2) ? (flags + (g + 1)*64 + 2*l31 + bh) : (flags + 3*64);

  const int sbi = tid >> 3, skc = tid & 7;
  const int swz = (sbi & 7) << 4;
  char* dstI = smem + sbi*1024;            // h_in  (region0) row
  char* dstP = smem + 32768 + sbi*1024;    // h_prev (region1) row
  float* part = (float*)(smem + 65536);    // 32KB partial area

  // prologue: stage h_in[0] for layers 1,2 into region0 (serial, one-time)
  if (g > 0) {
    if (wv == 0) {
      for (;;) {
        int v = __hip_atomic_load(fup, __ATOMIC_RELAXED, __HIP_MEMORY_SCOPE_AGENT);
        if (__all(v >= 1)) break;
        __builtin_amdgcn_s_sleep(2);
      }
    }
    asm volatile("" ::: "memory");
    __syncthreads();
    size_t ebase = ((size_t)((g-1)*SLOTS + 0) * 64 + bh*32 + sbi) * 512;
    if (big) {
      const u64x2* src = (const u64x2*)(ringq + (ebase >> 2));
      #pragma unroll
      for (int j = 0; j < 8; ++j) {
        u64x2 v = src[j*8 + skc];
        *(u64x2*)(dstI + (((j*8 + skc) * 16) ^ swz)) = v;
      }
    } else {
      const unsigned long long* src = ringq + (ebase >> 2);
      #pragma unroll
      for (int i = 0; i < 16; ++i) {
        unsigned long long v = __hip_atomic_load(src + (i*8 + skc), __ATOMIC_RELAXED, __HIP_MEMORY_SCOPE_AGENT);
        *(unsigned long long*)(dstI + (((i*8 + skc) * 8) ^ swz)) = v;
      }
    }
  }

  for (int t = 0; t < TT; ++t) {
    const int slot = big ? t : (t & 7);
    const int pf = (g > 0 && t + 1 < TT) ? 1 : 0;

    // ---- single poll site: siblings t-1, upstream t+1 (prefetch), backpressure
    if (wv == 0) {
      for (;;) {
        int ok = 1;
        if (t >= 1) {
          int v = __hip_atomic_load(fsib, __ATOMIC_RELAXED, __HIP_MEMORY_SCOPE_AGENT);
          ok &= (v >= t);
        }
        if (pf) {
          int v = __hip_atomic_load(fup, __ATOMIC_RELAXED, __HIP_MEMORY_SCOPE_AGENT);
          ok &= (v >= t + 2);
        }
        if (!big && t >= RINGD) {
          int v = __hip_atomic_load(fdn, __ATOMIC_RELAXED, __HIP_MEMORY_SCOPE_AGENT);
          ok &= (v >= t - RINGD + 1);
        }
        if (__all(ok)) break;
        __builtin_amdgcn_s_sleep(2);
      }
    }
    asm volatile("" ::: "memory");
    __syncthreads();                                     // B1

    // ---- issue BOTH ring reads into registers; write h_prev now,
    //      h_in(t+1) after compute (latency hidden under MFMA).
    u64x2 vp2[8], vi2[8];
    unsigned long long vp1[16], vi1[16];
    if (big) {
      if (t > 0) {
        size_t eb0 = ((size_t)(g*SLOTS + (t-1)) * 64 + bh*32 + sbi) * 512;
        const u64x2* src = (const u64x2*)(ringq + (eb0 >> 2));
        #pragma unroll
        for (int j = 0; j < 8; ++j) vp2[j] = src[j*8 + skc];
      }
      if (pf) {
        size_t eb1 = ((size_t)((g-1)*SLOTS + (t+1)) * 64 + bh*32 + sbi) * 512;
        const u64x2* src = (const u64x2*)(ringq + (eb1 >> 2));
        #pragma unroll
        for (int j = 0; j < 8; ++j) vi2[j] = src[j*8 + skc];
      }
      if (t == 0) {
        #pragma unroll
        for (int i = 0; i < 16; ++i)
          *(unsigned long long*)(dstP + (((i*8 + skc) * 8) ^ swz)) = 0ULL;
      } else {
        #pragma unroll
        for (int j = 0; j < 8; ++j)
          *(u64x2*)(dstP + (((j*8 + skc) * 16) ^ swz)) = vp2[j];
      }
    } else {
      if (t > 0) {
        size_t eb0 = ((size_t)(g*SLOTS + ((t-1) & 7)) * 64 + bh*32 + sbi) * 512;
        const unsigned long long* src = ringq + (eb0 >> 2);
        #pragma unroll
        for (int i = 0; i < 16; ++i)
          vp1[i] = __hip_atomic_load(src + (i*8 + skc), __ATOMIC_RELAXED, __HIP_MEMORY_SCOPE_AGENT);
      }
      if (pf) {
        size_t eb1 = ((size_t)((g-1)*SLOTS + ((t+1) & 7)) * 64 + bh*32 + sbi) * 512;
        const unsigned long long* src = ringq + (eb1 >> 2);
        #pragma unroll
        for (int i = 0; i < 16; ++i)
          vi1[i] = __hip_atomic_load(src + (i*8 + skc), __ATOMIC_RELAXED, __HIP_MEMORY_SCOPE_AGENT);
      }
      if (t == 0) {
        #pragma unroll
        for (int i = 0; i < 16; ++i)
          *(unsigned long long*)(dstP + (((i*8 + skc) * 8) ^ swz)) = 0ULL;
      } else {
        #pragma unroll
        for (int i = 0; i < 16; ++i)
          *(unsigned long long*)(dstP + (((i*8 + skc) * 8) ^ swz)) = vp1[i];
      }
    }
    __syncthreads();                                     // B2

    f32x4 acc[2][4];
    #pragma unroll
    for (int a = 0; a < 2; ++a) {
      #pragma unroll
      for (int b = 0; b < 4; ++b) { f32x4 z = {0.f, 0.f, 0.f, 0.f}; acc[a][b] = z; }
    }
    if (g == 0) compute_tiles<4>(warr, smem + 32768, wv, ln15, kgrp, acc);
    else        compute_tiles<8>(warr, smem,         wv, ln15, kgrp, acc);
    __syncthreads();                                     // B3 (region0 free)

    // deferred prefetch write: h_in(t+1) -> region0
    if (pf) {
      if (big) {
        #pragma unroll
        for (int j = 0; j < 8; ++j)
          *(u64x2*)(dstI + (((j*8 + skc) * 16) ^ swz)) = vi2[j];
      } else {
        #pragma unroll
        for (int i = 0; i < 16; ++i)
          *(unsigned long long*)(dstI + (((i*8 + skc) * 8) ^ swz)) = vi1[i];
      }
    }
    // cross-wave K-partial reduce via dedicated LDS area
    #pragma unroll
    for (int bt = 0; bt < 2; ++bt) {
      #pragma unroll
      for (int gt = 0; gt < 4; ++gt) {
        #pragma unroll
        for (int rr = 0; rr < 4; ++rr) {
          int brow = bt*16 + kgrp*4 + rr;
          int jj   = gt*16 + ln15;
          part[(wv*32 + brow)*64 + (jj ^ ((brow & 3) << 4))] = acc[bt][gt][rr];
        }
      }
    }
    __syncthreads();                                     // B4

    float Gv[4][2];
    #pragma unroll
    for (int gt = 0; gt < 4; ++gt) {
      #pragma unroll
      for (int cc = 0; cc < 2; ++cc) {
        int jx = (gt*16 + n0 + cc) ^ ((eb & 3) << 4);
        Gv[gt][cc] = part[(0*32 + eb)*64 + jx] + part[(1*32 + eb)*64 + jx]
                   + part[(2*32 + eb)*64 + jx] + part[(3*32 + eb)*64 + jx]
                   + bsv[gt][cc];
      }
    }
    if (g == 0) {
      float xv = x[(size_t)bge * TT + t];
      #pragma unroll
      for (int gt = 0; gt < 4; ++gt) {
        Gv[gt][0] += xv * wxv[gt][0];
        Gv[gt][1] += xv * wxv[gt][1];
      }
    }
    float i0 = sigmf_(Gv[0][0]), f0 = sigmf_(Gv[1][0]), gA = tanhf_(Gv[2][0]), o0 = sigmf_(Gv[3][0]);
    float i1 = sigmf_(Gv[0][1]), f1 = sigmf_(Gv[1][1]), gB = tanhf_(Gv[2][1]), o1 = sigmf_(Gv[3][1]);
    cst0 = f0 * cst0 + i0 * gA;
    cst1 = f1 * cst1 + i1 * gB;
    float h0 = o0 * tanhf_(cst0);
    float h1 = o1 * tanhf_(cst1);
    unsigned int packed = (unsigned int)f2bf(h0) | ((unsigned int)f2bf(h1) << 16);
    size_t eidx = ((size_t)(g*SLOTS + slot) * 64 + bge) * 512 + nbase + n0;
    __hip_atomic_store(ringw + (eidx >> 1), packed, __ATOMIC_RELAXED, __HIP_MEMORY_SCOPE_AGENT);
    __syncthreads();                                     // B5: ring stores drained
    if (tid == 0)
      __hip_atomic_store(myflag, t + 1, __ATOMIC_RELEASE, __HIP_MEMORY_SCOPE_AGENT);
  }
}

// ---------------------------------------------------------------------------
extern "C" void kernel_launch(void* const* d_in, const int* in_sizes, int n_in,
                              void* d_out, int out_size, void* d_ws, size_t ws_size,
                              hipStream_t stream)
{
  const float* x    = (const float*)d_in[0];
  const float* wih1 = (const float*)d_in[1];
  const float* whh1 = (const float*)d_in[2];
  const float* bih1 = (const float*)d_in[3];
  const float* bhh1 = (const float*)d_in[4];
  const float* wih2 = (const float*)d_in[5];
  const float* whh2 = (const float*)d_in[6];
  const float* bih2 = (const float*)d_in[7];
  const float* bhh2 = (const float*)d_in[8];
  const float* wih3 = (const float*)d_in[9];
  const float* whh3 = (const float*)d_in[10];
  const float* bih3 = (const float*)d_in[11];
  const float* bhh3 = (const float*)d_in[12];
  const float* wlin = (const float*)d_in[13];
  const float* blin = (const float*)d_in[14];
  unsigned char* ws = (unsigned char*)d_ws;
  float* out = (float*)d_out;

  int big = (ws_size >= NEED_BIG) ? 1 : 0;

  hipLaunchKernelGGL(prep_kernel, dim3(8192), dim3(256), 0, stream,
                     wih1, whh1, bih1, bhh1, wih2, whh2, bih2, bhh2,
                     wih3, whh3, bih3, bhh3, ws);

  static_assert(NGRID == 193, "grid");
  void* kws = (void*)ws;  void* kx = (void*)x;  void* kw1 = (void*)wih1;
  void* kwl = (void*)wlin; void* kbl = (void*)blin; void* ko = (void*)out;
  void* args[] = { &kws, &kx, &kw1, &kwl, &kbl, &ko, &big };
  hipError_t lerr = hipLaunchCooperativeKernel((void*)rnn_kernel, dim3(NGRID),
                                               dim3(256), args, 0, stream);
  if (lerr != hipSuccess) {
    hipLaunchKernelGGL(rnn_kernel, dim3(NGRID), dim3(256), 0, stream,
                       ws, x, wih1, wlin, blin, out, big);
  }
}

// Round 6
// 3617.216 us; speedup vs baseline: 2.0187x; 2.0187x over previous
//
#include <hip/hip_runtime.h>
#include <cstdint>
#include <cstddef>

// ---------------------------------------------------------------------------
// Persistent pipelined 3-layer LSTM on MI355X — v6.
//  = R4 (verified 5181us) skeleton EXACTLY, one change: in big-ring mode,
//  data-embedded readiness (sentinel 0xFFFFFFFF, impossible for packed h
//  since |h|<1) replaces all flag polls/publishes. Fast path: plain cached
//  loads; on sentinel: retry via agent-scope atomics (bypass stale L1/L2).
//  prep re-fills ring sentinels every launch (replay-safe). Small-mode
//  fallback keeps the full R4 flag machinery.
// ---------------------------------------------------------------------------

typedef __attribute__((ext_vector_type(8))) short bf16x8;
typedef __attribute__((ext_vector_type(4))) float f32x4;
typedef __attribute__((ext_vector_type(2))) unsigned long long u64x2;

#define TT    1024
#define RINGD 8
#define NBL   64
#define NGRID (3*NBL + 1)
#define SENT  0xFFFFFFFFu

#define OFF_W1   0ULL
#define OFF_W2   (OFF_W1 + 2048ULL*512*2)
#define OFF_W3   (OFF_W2 + 2048ULL*1024*2)
#define OFF_BIAS (OFF_W3 + 2048ULL*1024*2)
#define OFF_FLAG (OFF_BIAS + 3ULL*2048*4)
#define OFF_RING (OFF_FLAG + 4096ULL)
#define NEED_BIG (OFF_RING + 3ULL*TT*64*512*2)

__device__ __forceinline__ unsigned short f2bf(float f) {
  unsigned int u = __float_as_uint(f);
  unsigned int r = (u + 0x7fffu + ((u >> 16) & 1u)) >> 16;   // RNE
  return (unsigned short)r;
}
__device__ __forceinline__ float bf2f(unsigned short h) {
  return __uint_as_float(((unsigned int)h) << 16);
}
__device__ __forceinline__ float sigmf_(float z) {
  return 1.f / (1.f + __expf(-z));
}
__device__ __forceinline__ float tanhf_(float z) {
  float t = __expf(-2.f * fabsf(z));
  float r = (1.f - t) / (1.f + t);
  return (z < 0.f) ? -r : r;
}

// ---------------------------------------------------------------------------
__global__ void prep_kernel(const float* __restrict__ wih1, const float* __restrict__ whh1,
                            const float* __restrict__ bih1, const float* __restrict__ bhh1,
                            const float* __restrict__ wih2, const float* __restrict__ whh2,
                            const float* __restrict__ bih2, const float* __restrict__ bhh2,
                            const float* __restrict__ wih3, const float* __restrict__ whh3,
                            const float* __restrict__ bih3, const float* __restrict__ bhh3,
                            unsigned char* ws, int big)
{
  unsigned short* w1 = (unsigned short*)(ws + OFF_W1);
  unsigned short* w2 = (unsigned short*)(ws + OFF_W2);
  unsigned short* w3 = (unsigned short*)(ws + OFF_W3);
  float* bias = (float*)(ws + OFF_BIAS);
  int*   flags = (int*)(ws + OFF_FLAG);
  int idx = blockIdx.x * 256 + threadIdx.x;   // grid covers 2048*1024
  int j = idx >> 10, k = idx & 1023;
  if (j < 2048) {
    float v2 = (k < 512) ? wih2[j*512 + k] : whh2[j*512 + (k - 512)];
    float v3 = (k < 512) ? wih3[j*512 + k] : whh3[j*512 + (k - 512)];
    w2[j*1024 + k] = f2bf(v2);
    w3[j*1024 + k] = f2bf(v3);
    if (k < 512) w1[j*512 + k] = f2bf(whh1[j*512 + k]);
  }
  if (idx < 2048) {
    bias[idx]        = bih1[idx] + bhh1[idx];
    bias[2048 + idx] = bih2[idx] + bhh2[idx];
    bias[4096 + idx] = bih3[idx] + bhh3[idx];
  }
  if (idx < 256) flags[idx] = 0;
  if (big) {
    // sentinel-fill the full ring: 3*TT*64*512*2 B = 12,582,912 uint4
    uint4* r4 = (uint4*)(ws + OFF_RING);
    uint4 s; s.x = SENT; s.y = SENT; s.z = SENT; s.w = SENT;
    for (size_t i = idx; i < 12582912ULL; i += 2097152ULL) r4[i] = s;
  }
}

// ---------------------------------------------------------------------------
// MFMA over resident weight fragments; A from swizzled LDS.
template<int KSTEPS>
__device__ __forceinline__ void compute_tiles(const bf16x8 (&warr)[32], const char* smemc,
                                              int wv, int ln15, int kgrp,
                                              f32x4 (&acc)[2][4])
{
  const int k0w = wv * (KSTEPS * 32);
  const int sw  = (ln15 & 7) << 4;
  #pragma unroll
  for (int s = 0; s < KSTEPS; ++s) {
    const int koff = k0w + s*32 + kgrp*8;
    const int r    = koff >> 9;          // 0 = h_in region, 1 = h_prev region
    const int kin  = koff & 511;
    const char* ab = smemc + r*32768;
    bf16x8 a0 = *(const bf16x8*)(ab + ((ln15*1024        + kin*2) ^ sw));
    bf16x8 a1 = *(const bf16x8*)(ab + (((ln15 + 16)*1024 + kin*2) ^ sw));
    #pragma unroll
    for (int gt = 0; gt < 4; ++gt) {
      acc[0][gt] = __builtin_amdgcn_mfma_f32_16x16x32_bf16(a0, warr[gt*KSTEPS + s], acc[0][gt], 0, 0, 0);
      acc[1][gt] = __builtin_amdgcn_mfma_f32_16x16x32_bf16(a1, warr[gt*KSTEPS + s], acc[1][gt], 0, 0, 0);
    }
  }
}

// ---------------------------------------------------------------------------
__global__ __launch_bounds__(256, 1) void rnn_kernel(
    unsigned char* ws, const float* __restrict__ x,
    const float* __restrict__ wih1, const float* __restrict__ wlin,
    const float* __restrict__ blin, float* __restrict__ out, int big)
{
  __shared__ __align__(128) char smem[65536];
  const int tid  = threadIdx.x;
  const int lane = tid & 63;
  const int wv   = tid >> 6;
  const int SLOTS = big ? TT : RINGD;
  int* flags = (int*)(ws + OFF_FLAG);
  unsigned int* ringw = (unsigned int*)(ws + OFF_RING);
  const unsigned long long* ringq = (const unsigned long long*)(ws + OFF_RING);

  // ------------------------- output-projection block -----------------------
  if (blockIdx.x == NGRID - 1) {
    float* wl = (float*)smem;            // 512 floats
    float* op = (float*)(smem + 4096);   // 64 x 4 partials
    if (tid < 128) ((f32x4*)wl)[tid] = ((const f32x4*)wlin)[tid];
    float blv = blin[0];
    __syncthreads();
    const int ob = tid >> 2, okq = tid & 3;
    const int* fup = flags + 2*64 + lane;
    for (int t = 0; t < TT; ++t) {
      if (!big && wv == 0) {
        for (;;) {
          int v = __hip_atomic_load(fup, __ATOMIC_RELAXED, __HIP_MEMORY_SCOPE_AGENT);
          if (__all(v >= t + 1)) break;
          __builtin_amdgcn_s_sleep(2);
        }
      }
      asm volatile("" ::: "memory");
      __syncthreads();
      const int slot = big ? t : (t & 7);
      size_t ebase = ((size_t)(2*SLOTS + slot) * 64 + ob) * 512 + (size_t)okq * 128;
      const unsigned long long* hp = ringq + (ebase >> 2);
      const float* wlp = wl + okq * 128;
      unsigned long long qv[32];
      if (big) {
        #pragma unroll
        for (int i = 0; i < 32; ++i) qv[i] = hp[i];
        for (;;) {
          int bad = 0;
          #pragma unroll
          for (int i = 0; i < 32; ++i)
            bad |= ((unsigned int)qv[i] == SENT) | ((unsigned int)(qv[i] >> 32) == SENT);
          if (!bad) break;
          __builtin_amdgcn_s_sleep(2);
          #pragma unroll
          for (int i = 0; i < 32; ++i)
            qv[i] = __hip_atomic_load(hp + i, __ATOMIC_RELAXED, __HIP_MEMORY_SCOPE_AGENT);
        }
      } else {
        #pragma unroll
        for (int i = 0; i < 32; ++i)
          qv[i] = __hip_atomic_load(hp + i, __ATOMIC_RELAXED, __HIP_MEMORY_SCOPE_AGENT);
      }
      float acc = 0.f;
      #pragma unroll
      for (int i = 0; i < 32; ++i) {
        acc += bf2f((unsigned short)(qv[i]      )) * wlp[i*4 + 0];
        acc += bf2f((unsigned short)(qv[i] >> 16)) * wlp[i*4 + 1];
        acc += bf2f((unsigned short)(qv[i] >> 32)) * wlp[i*4 + 2];
        acc += bf2f((unsigned short)(qv[i] >> 48)) * wlp[i*4 + 3];
      }
      op[ob*4 + okq] = acc;
      __syncthreads();
      if (tid < 64)
        out[(size_t)tid * TT + t] = op[tid*4] + op[tid*4+1] + op[tid*4+2] + op[tid*4+3] + blv;
      if (!big && tid == 0)
        __hip_atomic_store(flags + 3*64, t + 1, __ATOMIC_RELEASE, __HIP_MEMORY_SCOPE_AGENT);
      __syncthreads();
    }
    return;
  }

  // ------------------------------ layer blocks -----------------------------
  const int g  = blockIdx.x >> 6;          // 0..2
  const int q  = blockIdx.x & 63;
  const int bh = q & 1;                    // batch half
  const int nbase = (q >> 1) << 4;         // n-chunk * 16
  const unsigned short* Wg =
      (const unsigned short*)(ws + (g == 0 ? OFF_W1 : (g == 1 ? OFF_W2 : OFF_W3)));
  const float* biasg = (const float*)(ws + OFF_BIAS) + g * 2048;

  const int ln15 = lane & 15;
  const int kgrp = lane >> 4;

  // ---- resident weight fragments: 32 x bf16x8 = 128 VGPR/thread ----
  bf16x8 warr[32];
  if (g == 0) {
    #pragma unroll
    for (int gt = 0; gt < 4; ++gt)
      #pragma unroll
      for (int s = 0; s < 4; ++s)
        warr[gt*4 + s] = *(const bf16x8*)(Wg + (size_t)(gt*512 + nbase + ln15)*512
                                             + wv*128 + s*32 + kgrp*8);
  } else {
    #pragma unroll
    for (int gt = 0; gt < 4; ++gt)
      #pragma unroll
      for (int s = 0; s < 8; ++s)
        warr[gt*8 + s] = *(const bf16x8*)(Wg + (size_t)(gt*512 + nbase + ln15)*1024
                                             + wv*256 + s*32 + kgrp*8);
  }

  // epilogue cell ownership: thread -> (batch eb, n-pair n0,n0+1)
  const int eb  = tid >> 3;                // 0..31
  const int n0  = (tid & 7) << 1;          // 0,2,...,14
  const int bge = bh * 32 + eb;            // global batch
  float bsv[4][2], wxv[4][2];
  #pragma unroll
  for (int gt = 0; gt < 4; ++gt) {
    #pragma unroll
    for (int cc = 0; cc < 2; ++cc) {
      int jj = gt*512 + nbase + n0 + cc;
      bsv[gt][cc] = biasg[jj];
      wxv[gt][cc] = (g == 0) ? wih1[jj] : 0.f;
    }
  }
  float cst0 = 0.f, cst1 = 0.f;            // persistent c state

  // flags (small mode only): waits narrowed to same batch-half producers
  const int l31 = lane & 31;
  int* myflag = flags + g*64 + q;
  const int* fup  = flags + (g > 0 ? (g - 1)*64 : 0) + 2*l31 + bh;
  const int* fsib = flags + g*64 + 2*l31 + bh;
  const int* fdn  = (g < 2) ? (flags + (g + 1)*64 + 2*l31 + bh) : (flags + 3*64);

  const int sbi = tid >> 3, skc = tid & 7;
  const int swz = (sbi & 7) << 4;

  // big-mode stage: plain loads, sentinel check, atomic retry (bypass L1/L2)
  auto stage_big = [&](int gg, int tick, int r) {
    size_t ebase = ((size_t)(gg*TT + tick) * 64 + bh*32 + sbi) * 512;
    const unsigned long long* src = ringq + (ebase >> 2);
    char* dst = smem + r*32768 + sbi*1024;
    unsigned long long v[16];
    #pragma unroll
    for (int i = 0; i < 8; ++i) {
      v[2*i]   = src[(i*8 + skc)*2];
      v[2*i+1] = src[(i*8 + skc)*2 + 1];
    }
    for (;;) {
      int bad = 0;
      #pragma unroll
      for (int i = 0; i < 16; ++i)
        bad |= ((unsigned int)v[i] == SENT) | ((unsigned int)(v[i] >> 32) == SENT);
      if (!bad) break;
      __builtin_amdgcn_s_sleep(2);
      #pragma unroll
      for (int i = 0; i < 8; ++i) {
        v[2*i]   = __hip_atomic_load(src + (i*8 + skc)*2,     __ATOMIC_RELAXED, __HIP_MEMORY_SCOPE_AGENT);
        v[2*i+1] = __hip_atomic_load(src + (i*8 + skc)*2 + 1, __ATOMIC_RELAXED, __HIP_MEMORY_SCOPE_AGENT);
      }
    }
    #pragma unroll
    for (int i = 0; i < 8; ++i) {
      u64x2 w; w[0] = v[2*i]; w[1] = v[2*i+1];
      *(u64x2*)(dst + (((i*8 + skc) * 16) ^ swz)) = w;
    }
  };
  auto stage_small = [&](int gg, int slot, int r) {
    size_t ebase = ((size_t)(gg*RINGD + slot) * 64 + bh*32 + sbi) * 512;
    const unsigned long long* src = ringq + (ebase >> 2);
    char* dst = smem + r*32768 + sbi*1024;
    unsigned long long v[16];
    #pragma unroll
    for (int i = 0; i < 16; ++i)
      v[i] = __hip_atomic_load(src + (i*8 + skc), __ATOMIC_RELAXED, __HIP_MEMORY_SCOPE_AGENT);
    #pragma unroll
    for (int i = 0; i < 16; ++i)
      *(unsigned long long*)(dst + (((i*8 + skc) * 8) ^ swz)) = v[i];
  };
  auto zero_region = [&](int r) {
    char* dst = smem + r*32768 + sbi*1024;
    #pragma unroll
    for (int i = 0; i < 16; ++i)
      *(unsigned long long*)(dst + (((i*8 + skc) * 8) ^ swz)) = 0ULL;
  };

  // prologue: stage h_in[0] for layers 1,2
  if (g > 0) {
    if (big) {
      stage_big(g - 1, 0, 0);              // sentinel retry = the wait
    } else {
      if (wv == 0) {
        for (;;) {
          int v = __hip_atomic_load(fup, __ATOMIC_RELAXED, __HIP_MEMORY_SCOPE_AGENT);
          if (__all(v >= 1)) break;
          __builtin_amdgcn_s_sleep(2);
        }
      }
      asm volatile("" ::: "memory");
      __syncthreads();
      stage_small(g - 1, 0, 0);
    }
  }

  for (int t = 0; t < TT; ++t) {
    const int slot = big ? t : (t & 7);
    // small mode: sibling + backpressure polls. big mode: none (sentinels).
    if (!big && wv == 0) {
      for (;;) {
        int ok = 1;
        if (t >= 1) {
          int v = __hip_atomic_load(fsib, __ATOMIC_RELAXED, __HIP_MEMORY_SCOPE_AGENT);
          ok &= (v >= t);
        }
        if (t >= RINGD) {
          int v = __hip_atomic_load(fdn, __ATOMIC_RELAXED, __HIP_MEMORY_SCOPE_AGENT);
          ok &= (v >= t - RINGD + 1);
        }
        if (__all(ok)) break;
        __builtin_amdgcn_s_sleep(2);
      }
    }
    asm volatile("" ::: "memory");
    __syncthreads();                                     // B1
    const int hr = (g == 0) ? 0 : 1;
    if (t == 0)       zero_region(hr);
    else if (big)     stage_big(g, t - 1, hr);
    else              stage_small(g, (t - 1) & 7, hr);
    __syncthreads();                                     // B2

    f32x4 acc[2][4];
    #pragma unroll
    for (int a = 0; a < 2; ++a) {
      #pragma unroll
      for (int b = 0; b < 4; ++b) { f32x4 z = {0.f, 0.f, 0.f, 0.f}; acc[a][b] = z; }
    }
    if (g == 0) compute_tiles<4>(warr, smem, wv, ln15, kgrp, acc);
    else        compute_tiles<8>(warr, smem, wv, ln15, kgrp, acc);
    __syncthreads();                                     // B3 (region0 now free)

    // cross-wave K-partial reduce via LDS (overlays region0)
    float* part = (float*)smem;
    #pragma unroll
    for (int bt = 0; bt < 2; ++bt) {
      #pragma unroll
      for (int gt = 0; gt < 4; ++gt) {
        #pragma unroll
        for (int rr = 0; rr < 4; ++rr) {
          int brow = bt*16 + kgrp*4 + rr;
          int jj   = gt*16 + ln15;
          part[(wv*32 + brow)*64 + (jj ^ ((brow & 3) << 4))] = acc[bt][gt][rr];
        }
      }
    }
    __syncthreads();                                     // B4

    float Gv[4][2];
    #pragma unroll
    for (int gt = 0; gt < 4; ++gt) {
      #pragma unroll
      for (int cc = 0; cc < 2; ++cc) {
        int jx = (gt*16 + n0 + cc) ^ ((eb & 3) << 4);
        Gv[gt][cc] = part[(0*32 + eb)*64 + jx] + part[(1*32 + eb)*64 + jx]
                   + part[(2*32 + eb)*64 + jx] + part[(3*32 + eb)*64 + jx]
                   + bsv[gt][cc];
      }
    }
    if (g == 0) {
      float xv = x[(size_t)bge * TT + t];
      #pragma unroll
      for (int gt = 0; gt < 4; ++gt) {
        Gv[gt][0] += xv * wxv[gt][0];
        Gv[gt][1] += xv * wxv[gt][1];
      }
    }
    float i0 = sigmf_(Gv[0][0]), f0 = sigmf_(Gv[1][0]), gA = tanhf_(Gv[2][0]), o0 = sigmf_(Gv[3][0]);
    float i1 = sigmf_(Gv[0][1]), f1 = sigmf_(Gv[1][1]), gB = tanhf_(Gv[2][1]), o1 = sigmf_(Gv[3][1]);
    cst0 = f0 * cst0 + i0 * gA;
    cst1 = f1 * cst1 + i1 * gB;
    float h0 = o0 * tanhf_(cst0);
    float h1 = o1 * tanhf_(cst1);
    unsigned int packed = (unsigned int)f2bf(h0) | ((unsigned int)f2bf(h1) << 16);
    size_t eidx = ((size_t)(g*SLOTS + slot) * 64 + bge) * 512 + nbase + n0;
    __hip_atomic_store(ringw + (eidx >> 1), packed, __ATOMIC_RELAXED, __HIP_MEMORY_SCOPE_AGENT);
    __syncthreads();                                     // B5: all h stores drained
    if (!big && tid == 0)
      __hip_atomic_store(myflag, t + 1, __ATOMIC_RELEASE, __HIP_MEMORY_SCOPE_AGENT);

    // prefetch h_in[t+1] (post-publish: upstream jitter absorbed off-path)
    if (g > 0 && t + 1 < TT) {
      if (big) {
        __syncthreads();                                 // B6 (region0 reuse gate)
        stage_big(g - 1, t + 1, 0);
      } else {
        if (wv == 0) {
          for (;;) {
            int v = __hip_atomic_load(fup, __ATOMIC_RELAXED, __HIP_MEMORY_SCOPE_AGENT);
            if (__all(v >= t + 2)) break;
            __builtin_amdgcn_s_sleep(2);
          }
        }
        asm volatile("" ::: "memory");
        __syncthreads();                                 // B6
        stage_small(g - 1, (t + 1) & 7, 0);
      }
    }
    __syncthreads();                                     // B7
  }
}

// ---------------------------------------------------------------------------
extern "C" void kernel_launch(void* const* d_in, const int* in_sizes, int n_in,
                              void* d_out, int out_size, void* d_ws, size_t ws_size,
                              hipStream_t stream)
{
  const float* x    = (const float*)d_in[0];
  const float* wih1 = (const float*)d_in[1];
  const float* whh1 = (const float*)d_in[2];
  const float* bih1 = (const float*)d_in[3];
  const float* bhh1 = (const float*)d_in[4];
  const float* wih2 = (const float*)d_in[5];
  const float* whh2 = (const float*)d_in[6];
  const float* bih2 = (const float*)d_in[7];
  const float* bhh2 = (const float*)d_in[8];
  const float* wih3 = (const float*)d_in[9];
  const float* whh3 = (const float*)d_in[10];
  const float* bih3 = (const float*)d_in[11];
  const float* bhh3 = (const float*)d_in[12];
  const float* wlin = (const float*)d_in[13];
  const float* blin = (const float*)d_in[14];
  unsigned char* ws = (unsigned char*)d_ws;
  float* out = (float*)d_out;

  int big = (ws_size >= NEED_BIG) ? 1 : 0;

  hipLaunchKernelGGL(prep_kernel, dim3(8192), dim3(256), 0, stream,
                     wih1, whh1, bih1, bhh1, wih2, whh2, bih2, bhh2,
                     wih3, whh3, bih3, bhh3, ws, big);

  static_assert(NGRID == 193, "grid");
  void* kws = (void*)ws;  void* kx = (void*)x;  void* kw1 = (void*)wih1;
  void* kwl = (void*)wlin; void* kbl = (void*)blin; void* ko = (void*)out;
  void* args[] = { &kws, &kx, &kw1, &kwl, &kbl, &ko, &big };
  hipError_t lerr = hipLaunchCooperativeKernel((void*)rnn_kernel, dim3(NGRID),
                                               dim3(256), args, 0, stream);
  if (lerr != hipSuccess) {
    hipLaunchKernelGGL(rnn_kernel, dim3(NGRID), dim3(256), 0, stream,
                       ws, x, wih1, wlin, blin, out, big);
  }
}